// Round 6
// baseline (297.836 us; speedup 1.0000x reference)
//
#include <hip/hip_runtime.h>
#include <hip/hip_bf16.h>
#include <math.h>

// MoE Router V2: x(16384,2048) fp32, W(128,2048) fp32, bias(128) fp32
// out = [weights(16384,8) fp32 | indices(16384,8) as fp32]
//
// R6 = R5's barrier-free fused structure + R3's BIT-EXACT accumulation order.
//   R5 failed on an index boundary flip: chaining all 64 k-chunks through one
//   MFMA accumulator rounds differently (~1e-7) than R3's 4 split-K chains of
//   16 chunks summed ((p0+p1)+p2)+p3 in VALU; one token's 8th/9th gap is that
//   small. R6 restores: per-slice fresh acc (16 chunks, same 6-product order)
//   then incremental VALU sum in slice order -> logits bit-identical to the
//   PASSING R3/R4, so selection is guaranteed identical.
//   - w_planes: split W into 3 bf16 planes once (same split3), stored in
//     B-fragment layout; main kernel loads B-frags via global_load_dwordx4
//     from L2. No W LDS.
//   - moe_router_fused: block = 32 tok x 128 exp, wave = 32x32 (2x2 verified
//     16x16x32 bf16 tiles); x loaded global->VGPR in A-frag order, split3
//     in-register. K-loop: zero LDS, zero barriers, c+1 register prefetch.
//     Epilogue: logits -> LDS (2-way banks = free), one barrier, verified
//     shuffle softmax/top-8 (code identical to passing rounds).

#define NE     128
#define TOKT   32
#define DMODEL 2048
#define NCHUNK 64            // 2048 / 32
#define NSLICE 4             // split-K slices (bit-exact vs R3)
#define CPS    16            // chunks per slice
#define PSTRIDE 262144       // plane stride in wfrag, shorts (64*8*512)

typedef __attribute__((ext_vector_type(8))) short short8;
typedef __attribute__((ext_vector_type(4))) float f32x4;

union S8 { short s[8]; short8 v; };

// split one fp32 into 3 truncated bf16 planes (exact residuals)
__device__ __forceinline__ void split3(float f, S8& hi, S8& mi, S8& lo, int j) {
  const unsigned u0 = __float_as_uint(f);
  const float hif = __uint_as_float(u0 & 0xFFFF0000u);
  const float r1 = f - hif;                      // exact
  const unsigned u1 = __float_as_uint(r1);
  const float mif = __uint_as_float(u1 & 0xFFFF0000u);
  const float r2 = r1 - mif;                     // exact
  hi.s[j] = (short)(u0 >> 16);
  mi.s[j] = (short)(u1 >> 16);
  lo.s[j] = (short)(__float_as_uint(r2) >> 16);
}

__device__ __forceinline__ void split8(const float4& a0, const float4& a1,
                                       S8& hi, S8& mi, S8& lo) {
  split3(a0.x, hi, mi, lo, 0); split3(a0.y, hi, mi, lo, 1);
  split3(a0.z, hi, mi, lo, 2); split3(a0.w, hi, mi, lo, 3);
  split3(a1.x, hi, mi, lo, 4); split3(a1.y, hi, mi, lo, 5);
  split3(a1.z, hi, mi, lo, 6); split3(a1.w, hi, mi, lo, 7);
}

// wfrag[p][c][g][lane][j]: plane p of
//   W[g*16 + (lane&15)][c*32 + (lane>>4)*8 + j]  == B-frag for 16x16x32
__global__ void w_planes(const float* __restrict__ w, short* __restrict__ wfrag) {
  const int c = blockIdx.x;          // k-chunk 0..63
  const int t = threadIdx.x;         // 256 threads
  const int e = t >> 1;              // expert 0..127
  const int h = t & 1;               // k half (0/16)
  const float* gw = w + (size_t)e * DMODEL + c * 32 + h * 16;
  const int g = e >> 4;
#pragma unroll
  for (int r2 = 0; r2 < 2; ++r2) {
    const float4 a0 = *(const float4*)(gw + r2 * 8);
    const float4 a1 = *(const float4*)(gw + r2 * 8 + 4);
    S8 hi, mi, lo;
    split8(a0, a1, hi, mi, lo);
    const int quad = 2 * h + r2;
    const int lane = quad * 16 + (e & 15);
    short* base = wfrag + ((size_t)c * 8 + g) * 512 + lane * 8;
    *(short8*)(base)               = hi.v;
    *(short8*)(base + PSTRIDE)     = mi.v;
    *(short8*)(base + 2 * PSTRIDE) = lo.v;
  }
}

__global__ __launch_bounds__(256) void moe_router_fused(
    const float* __restrict__ x, const short* __restrict__ wfrag,
    const float* __restrict__ bias,
    float* __restrict__ outW, float* __restrict__ outI, int N) {
  __shared__ float ls[TOKT][NE + 4];
  const int tid  = threadIdx.x;
  const int wv   = tid >> 6;       // wave: experts [32*wv, 32*wv+32)
  const int lane = tid & 63;
  const int quad = lane >> 4;
  const int l16  = lane & 15;
  const size_t tokBase = (size_t)blockIdx.x * TOKT;

  const float* xb = x + (tokBase + l16) * DMODEL + quad * 8;
  const short* wb = wfrag + ((size_t)(wv * 2)) * 512 + lane * 8;  // group wv*2, +512 for nt=1

  // prefetch chunk 0
  float4 px[4];
  short8 pw[6];
  px[0] = *(const float4*)(xb);
  px[1] = *(const float4*)(xb + 4);
  px[2] = *(const float4*)(xb + 16 * DMODEL);
  px[3] = *(const float4*)(xb + 16 * DMODEL + 4);
#pragma unroll
  for (int nt = 0; nt < 2; ++nt)
#pragma unroll
    for (int p = 0; p < 3; ++p)
      pw[nt * 3 + p] = *(const short8*)(wb + (size_t)p * PSTRIDE + nt * 512);

  f32x4 logit[2][2];

  for (int s = 0; s < NSLICE; ++s) {
    // fresh accumulator per K-slice (matches R3's split-K partial)
    f32x4 acc[2][2];
#pragma unroll
    for (int i = 0; i < 2; ++i)
#pragma unroll
      for (int j = 0; j < 2; ++j) acc[i][j] = (f32x4)(0.f);

#pragma unroll 4
    for (int j = 0; j < CPS; ++j) {
      const int c = s * CPS + j;
      // consume prefetched regs into fragments
      short8 af[2][3], bf[2][3];
      {
        S8 hi, mi, lo;
        split8(px[0], px[1], hi, mi, lo);
        af[0][0] = hi.v; af[0][1] = mi.v; af[0][2] = lo.v;
        split8(px[2], px[3], hi, mi, lo);
        af[1][0] = hi.v; af[1][1] = mi.v; af[1][2] = lo.v;
      }
#pragma unroll
      for (int nt = 0; nt < 2; ++nt)
#pragma unroll
        for (int p = 0; p < 3; ++p)
          bf[nt][p] = pw[nt * 3 + p];

      // prefetch chunk c+1 (clamped; latency hides behind the 24 MFMAs)
      {
        const int cn = (c + 1 < NCHUNK) ? c + 1 : c;
        const float* xn = xb + cn * 32;
        px[0] = *(const float4*)(xn);
        px[1] = *(const float4*)(xn + 4);
        px[2] = *(const float4*)(xn + 16 * DMODEL);
        px[3] = *(const float4*)(xn + 16 * DMODEL + 4);
#pragma unroll
        for (int nt = 0; nt < 2; ++nt)
#pragma unroll
          for (int p = 0; p < 3; ++p)
            pw[nt * 3 + p] = *(const short8*)(wb + (size_t)p * PSTRIDE
                                              + (size_t)cn * 4096 + nt * 512);
      }

      // 6-plane MFMAs per 16x16 tile — same per-tile product order as R3
#pragma unroll
      for (int nt = 0; nt < 2; ++nt)
#pragma unroll
        for (int mt = 0; mt < 2; ++mt) {
          f32x4 cc = acc[mt][nt];
          cc = __builtin_amdgcn_mfma_f32_16x16x32_bf16(af[mt][0], bf[nt][0], cc, 0, 0, 0);
          cc = __builtin_amdgcn_mfma_f32_16x16x32_bf16(af[mt][0], bf[nt][1], cc, 0, 0, 0);
          cc = __builtin_amdgcn_mfma_f32_16x16x32_bf16(af[mt][1], bf[nt][0], cc, 0, 0, 0);
          cc = __builtin_amdgcn_mfma_f32_16x16x32_bf16(af[mt][0], bf[nt][2], cc, 0, 0, 0);
          cc = __builtin_amdgcn_mfma_f32_16x16x32_bf16(af[mt][2], bf[nt][0], cc, 0, 0, 0);
          cc = __builtin_amdgcn_mfma_f32_16x16x32_bf16(af[mt][1], bf[nt][1], cc, 0, 0, 0);
          acc[mt][nt] = cc;
        }
    }

    // slice combine in slice order: logit = ((s0+s1)+s2)+s3  (bit-exact vs R3 router)
    if (s == 0) {
#pragma unroll
      for (int mt = 0; mt < 2; ++mt)
#pragma unroll
        for (int nt = 0; nt < 2; ++nt) logit[mt][nt] = acc[mt][nt];
    } else {
#pragma unroll
      for (int mt = 0; mt < 2; ++mt)
#pragma unroll
        for (int nt = 0; nt < 2; ++nt) logit[mt][nt] += acc[mt][nt];
    }
  }

  // ---- epilogue: logits -> LDS (C/D: col=lane&15 = expert, row=quad*4+reg = token)
#pragma unroll
  for (int mt = 0; mt < 2; ++mt)
#pragma unroll
    for (int nt = 0; nt < 2; ++nt)
#pragma unroll
      for (int reg = 0; reg < 4; ++reg)
        ls[mt * 16 + quad * 4 + reg][wv * 32 + nt * 16 + l16] = logit[mt][nt][reg];
  __syncthreads();

  // ---- router: this wave handles tokens [8*wv, 8*wv+8); code identical to
  //      the R1-R4 passing router.
  const float badd0 = bias[lane];
  const float badd1 = bias[lane + 64];
#pragma unroll 1
  for (int t = 0; t < 8; ++t) {
    const int token = wv * 8 + t;
    const float lg0 = ls[token][lane];
    const float lg1 = ls[token][lane + 64];

    float m = fmaxf(lg0, lg1);
#pragma unroll
    for (int off = 1; off < 64; off <<= 1) m = fmaxf(m, __shfl_xor(m, off));
    const float ev0 = __expf(lg0 - m);
    const float ev1 = __expf(lg1 - m);
    float zs = ev0 + ev1;
#pragma unroll
    for (int off = 1; off < 64; off <<= 1) zs += __shfl_xor(zs, off);
    const float s0 = ev0 / zs;
    const float s1 = ev1 / zs;

    float b0 = s0 + badd0;
    float b1 = s1 + badd1;

    float myv = 0.f;
    int myi = 0;
    float ss = 0.f;
#pragma unroll
    for (int rnd = 0; rnd < 8; ++rnd) {
      float key; int idx;
      if (b0 >= b1) { key = b0; idx = lane; }
      else          { key = b1; idx = lane + 64; }
#pragma unroll
      for (int off = 1; off < 64; off <<= 1) {
        const float k2 = __shfl_xor(key, off);
        const int   i2 = __shfl_xor(idx, off);
        if (k2 > key || (k2 == key && i2 < idx)) { key = k2; idx = i2; }
      }
      const float cand = (idx < 64) ? s0 : s1;
      const float sw = __shfl(cand, idx & 63);
      ss = fmaf(sw, sw, ss);
      if (lane == rnd) { myv = sw; myi = idx; }
      if (lane == (idx & 63)) { if (idx < 64) b0 = -INFINITY; else b1 = -INFINITY; }
    }

    const float inv = 1.f / sqrtf(ss);
    if (lane < 8) {
      outW[(tokBase + token) * 8 + lane] = myv * inv;
      outI[(tokBase + token) * 8 + lane] = (float)myi;
    }
  }
}

extern "C" void kernel_launch(void* const* d_in, const int* in_sizes, int n_in,
                              void* d_out, int out_size, void* d_ws, size_t ws_size,
                              hipStream_t stream) {
  const float* x    = (const float*)d_in[0];
  const float* w    = (const float*)d_in[1];
  const float* bias = (const float*)d_in[2];
  float* out = (float*)d_out;

  const int N = in_sizes[0] / DMODEL;  // 16384 tokens
  short* wfrag = (short*)d_ws;         // 3 * 64 * 8 * 512 shorts = 1.5 MB

  w_planes<<<NCHUNK, 256, 0, stream>>>(w, wfrag);
  moe_router_fused<<<N / TOKT, 256, 0, stream>>>(x, wfrag, bias,
                                                 out, out + (size_t)N * 8, N);
}

// Round 7
// 275.970 us; speedup vs baseline: 1.0792x; 1.0792x over previous
//
#include <hip/hip_runtime.h>
#include <hip/hip_bf16.h>
#include <math.h>

// MoE Router V2: x(16384,2048) fp32, W(128,2048) fp32, bias(128) fp32
// out = [weights(16384,8) fp32 | indices(16384,8) as fp32]
//
// R7: wave-per-slice fused router. Block = 32 tokens, 4 waves; wave s
//   computes split-K slice s (16 chunks) over all 128 experts -> acc chains
//   are BIT-IDENTICAL to R3/R6 (same split3 planes, same 6-product order,
//   fresh acc per slice). Slice combine = serialized LDS RMW with barriers,
//   left-assoc ((s0+s1)+s2)+s3 -> logits bit-identical to passing R6.
//   vs R6: x split once per chunk per wave (was 4x redundant across waves),
//   W-frag 4-slot ring (2 groups lookahead), x 1-chunk prefetch.
// w_planes: split W into 3 bf16 planes once, B-frag layout (unchanged).

#define NE     128
#define TOKT   32
#define DMODEL 2048
#define NSLICE 4
#define CPS    16            // chunks per slice
#define PSTRIDE 262144       // plane stride in wfrag, shorts (64*8*512)

typedef __attribute__((ext_vector_type(8))) short short8;
typedef __attribute__((ext_vector_type(4))) float f32x4;

union S8 { short s[8]; short8 v; };

// split one fp32 into 3 truncated bf16 planes (exact residuals)
__device__ __forceinline__ void split3(float f, S8& hi, S8& mi, S8& lo, int j) {
  const unsigned u0 = __float_as_uint(f);
  const float hif = __uint_as_float(u0 & 0xFFFF0000u);
  const float r1 = f - hif;                      // exact
  const unsigned u1 = __float_as_uint(r1);
  const float mif = __uint_as_float(u1 & 0xFFFF0000u);
  const float r2 = r1 - mif;                     // exact
  hi.s[j] = (short)(u0 >> 16);
  mi.s[j] = (short)(u1 >> 16);
  lo.s[j] = (short)(__float_as_uint(r2) >> 16);
}

__device__ __forceinline__ void split8(const float4& a0, const float4& a1,
                                       S8& hi, S8& mi, S8& lo) {
  split3(a0.x, hi, mi, lo, 0); split3(a0.y, hi, mi, lo, 1);
  split3(a0.z, hi, mi, lo, 2); split3(a0.w, hi, mi, lo, 3);
  split3(a1.x, hi, mi, lo, 4); split3(a1.y, hi, mi, lo, 5);
  split3(a1.z, hi, mi, lo, 6); split3(a1.w, hi, mi, lo, 7);
}

// wfrag[p][c][g][lane][j]: plane p of
//   W[g*16 + (lane&15)][c*32 + (lane>>4)*8 + j]  == B-frag for 16x16x32
__global__ void w_planes(const float* __restrict__ w, short* __restrict__ wfrag) {
  const int c = blockIdx.x;          // k-chunk 0..63
  const int t = threadIdx.x;         // 256 threads
  const int e = t >> 1;              // expert 0..127
  const int h = t & 1;               // k half (0/16)
  const float* gw = w + (size_t)e * DMODEL + c * 32 + h * 16;
  const int g = e >> 4;
#pragma unroll
  for (int r2 = 0; r2 < 2; ++r2) {
    const float4 a0 = *(const float4*)(gw + r2 * 8);
    const float4 a1 = *(const float4*)(gw + r2 * 8 + 4);
    S8 hi, mi, lo;
    split8(a0, a1, hi, mi, lo);
    const int quad = 2 * h + r2;
    const int lane = quad * 16 + (e & 15);
    short* base = wfrag + ((size_t)c * 8 + g) * 512 + lane * 8;
    *(short8*)(base)               = hi.v;
    *(short8*)(base + PSTRIDE)     = mi.v;
    *(short8*)(base + 2 * PSTRIDE) = lo.v;
  }
}

__global__ __launch_bounds__(256, 2) void moe_router_fused(
    const float* __restrict__ x, const short* __restrict__ wfrag,
    const float* __restrict__ bias,
    float* __restrict__ outW, float* __restrict__ outI, int N) {
  __shared__ float ls[TOKT][NE + 4];
  const int tid  = threadIdx.x;
  const int wv   = tid >> 6;       // wave = K-slice id
  const int lane = tid & 63;
  const int quad = lane >> 4;
  const int l16  = lane & 15;
  const size_t tokBase = (size_t)blockIdx.x * TOKT;
  const int c0 = wv * CPS;         // this wave's first chunk

  const float* xb = x + (tokBase + l16) * DMODEL + quad * 8 + c0 * 32;
  const short* wb = wfrag + (size_t)c0 * 4096 + lane * 8;

  f32x4 acc[2][8];                 // [tok-tile][expert-group]
#pragma unroll
  for (int i = 0; i < 2; ++i)
#pragma unroll
    for (int g = 0; g < 8; ++g) acc[i][g] = (f32x4)(0.f);

  // prefetch: x chunk 0; W groups 0,1 of chunk 0 (ring slots 0,1)
  float4 px[4];
  short8 pw[4][3];
  px[0] = *(const float4*)(xb);
  px[1] = *(const float4*)(xb + 4);
  px[2] = *(const float4*)(xb + 16 * DMODEL);
  px[3] = *(const float4*)(xb + 16 * DMODEL + 4);
#pragma unroll
  for (int g = 0; g < 2; ++g)
#pragma unroll
    for (int p = 0; p < 3; ++p)
      pw[g][p] = *(const short8*)(wb + (size_t)p * PSTRIDE + g * 512);

#pragma unroll 2
  for (int j = 0; j < CPS; ++j) {
    // split this chunk's x into A-frag planes (same split3 values as R3/R6)
    short8 af[2][3];
    {
      S8 hi, mi, lo;
      split8(px[0], px[1], hi, mi, lo);
      af[0][0] = hi.v; af[0][1] = mi.v; af[0][2] = lo.v;
      split8(px[2], px[3], hi, mi, lo);
      af[1][0] = hi.v; af[1][1] = mi.v; af[1][2] = lo.v;
    }
    // prefetch next chunk's x (clamped)
    {
      const int jn = (j + 1 < CPS) ? j + 1 : j;
      const float* xn = xb + jn * 32;
      px[0] = *(const float4*)(xn);
      px[1] = *(const float4*)(xn + 4);
      px[2] = *(const float4*)(xn + 16 * DMODEL);
      px[3] = *(const float4*)(xn + 16 * DMODEL + 4);
    }
#pragma unroll
    for (int g = 0; g < 8; ++g) {
      // prefetch W-frags 2 groups ahead into ring slot (g+2)&3
      {
        int jj = j, gg = g + 2;
        if (gg >= 8) { gg -= 8; jj = (j + 1 < CPS) ? j + 1 : j; }
        const short* pb = wb + (size_t)jj * 4096 + gg * 512;
        pw[(g + 2) & 3][0] = *(const short8*)(pb);
        pw[(g + 2) & 3][1] = *(const short8*)(pb + PSTRIDE);
        pw[(g + 2) & 3][2] = *(const short8*)(pb + 2 * PSTRIDE);
      }
      // 6-plane MFMAs per tok-tile — same per-tile product order as R3/R6
#pragma unroll
      for (int mt = 0; mt < 2; ++mt) {
        f32x4 cc = acc[mt][g];
        cc = __builtin_amdgcn_mfma_f32_16x16x32_bf16(af[mt][0], pw[g & 3][0], cc, 0, 0, 0);
        cc = __builtin_amdgcn_mfma_f32_16x16x32_bf16(af[mt][0], pw[g & 3][1], cc, 0, 0, 0);
        cc = __builtin_amdgcn_mfma_f32_16x16x32_bf16(af[mt][1], pw[g & 3][0], cc, 0, 0, 0);
        cc = __builtin_amdgcn_mfma_f32_16x16x32_bf16(af[mt][0], pw[g & 3][2], cc, 0, 0, 0);
        cc = __builtin_amdgcn_mfma_f32_16x16x32_bf16(af[mt][2], pw[g & 3][0], cc, 0, 0, 0);
        cc = __builtin_amdgcn_mfma_f32_16x16x32_bf16(af[mt][1], pw[g & 3][1], cc, 0, 0, 0);
        acc[mt][g] = cc;
      }
    }
  }

  // ---- slice combine: serialized LDS RMW, left-assoc ((s0+s1)+s2)+s3 ----
  // C/D layout: col = l16 (expert within group), row = quad*4+reg (token)
#pragma unroll 1
  for (int s = 0; s < NSLICE; ++s) {
    if (wv == s) {
#pragma unroll
      for (int mt = 0; mt < 2; ++mt)
#pragma unroll
        for (int g = 0; g < 8; ++g)
#pragma unroll
          for (int reg = 0; reg < 4; ++reg) {
            const int row = mt * 16 + quad * 4 + reg;
            const int col = g * 16 + l16;
            if (s == 0) ls[row][col] = acc[mt][g][reg];
            else        ls[row][col] += acc[mt][g][reg];
          }
    }
    __syncthreads();
  }

  // ---- router: wave wv handles tokens [8*wv, 8*wv+8); identical to R6 ----
  const float badd0 = bias[lane];
  const float badd1 = bias[lane + 64];
#pragma unroll 1
  for (int t = 0; t < 8; ++t) {
    const int token = wv * 8 + t;
    const float lg0 = ls[token][lane];
    const float lg1 = ls[token][lane + 64];

    float m = fmaxf(lg0, lg1);
#pragma unroll
    for (int off = 1; off < 64; off <<= 1) m = fmaxf(m, __shfl_xor(m, off));
    const float ev0 = __expf(lg0 - m);
    const float ev1 = __expf(lg1 - m);
    float zs = ev0 + ev1;
#pragma unroll
    for (int off = 1; off < 64; off <<= 1) zs += __shfl_xor(zs, off);
    const float s0 = ev0 / zs;
    const float s1 = ev1 / zs;

    float b0 = s0 + badd0;
    float b1 = s1 + badd1;

    float myv = 0.f;
    int myi = 0;
    float ss = 0.f;
#pragma unroll
    for (int rnd = 0; rnd < 8; ++rnd) {
      float key; int idx;
      if (b0 >= b1) { key = b0; idx = lane; }
      else          { key = b1; idx = lane + 64; }
#pragma unroll
      for (int off = 1; off < 64; off <<= 1) {
        const float k2 = __shfl_xor(key, off);
        const int   i2 = __shfl_xor(idx, off);
        if (k2 > key || (k2 == key && i2 < idx)) { key = k2; idx = i2; }
      }
      const float cand = (idx < 64) ? s0 : s1;
      const float sw = __shfl(cand, idx & 63);
      ss = fmaf(sw, sw, ss);
      if (lane == rnd) { myv = sw; myi = idx; }
      if (lane == (idx & 63)) { if (idx < 64) b0 = -INFINITY; else b1 = -INFINITY; }
    }

    const float inv = 1.f / sqrtf(ss);
    if (lane < 8) {
      outW[(tokBase + token) * 8 + lane] = myv * inv;
      outI[(tokBase + token) * 8 + lane] = (float)myi;
    }
  }
}

extern "C" void kernel_launch(void* const* d_in, const int* in_sizes, int n_in,
                              void* d_out, int out_size, void* d_ws, size_t ws_size,
                              hipStream_t stream) {
  const float* x    = (const float*)d_in[0];
  const float* w    = (const float*)d_in[1];
  const float* bias = (const float*)d_in[2];
  float* out = (float*)d_out;

  const int N = in_sizes[0] / DMODEL;  // 16384 tokens
  short* wfrag = (short*)d_ws;         // 3 * 64 * 8 * 512 shorts = 1.5 MB

  w_planes<<<64, 256, 0, stream>>>(w, wfrag);
  moe_router_fused<<<N / TOKT, 256, 0, stream>>>(x, wfrag, bias,
                                                 out, out + (size_t)N * 8, N);
}